// Round 1
// baseline (159.906 us; speedup 1.0000x reference)
//
#include <hip/hip_runtime.h>

// TreeModel: complete binary tree, heap-ordered nodes (0 = root, children 2k+1/2k+2).
// out[0..16383]  = result[i] = dot(x[i], sum of deltas rows on root->leaf path)
// out[16384]     = sq[0] + sum_{n>=1} sq[n] / max(heights[n]-heights[parent], 1e-7)

constexpr int   N_LEAVES = 16384;
constexpr int   N_NODES  = 2 * N_LEAVES - 1;   // 32767
constexpr int   DIM      = 512;
constexpr float MIN_DIST = 1e-7f;

__global__ void zero_scalar_kernel(float* __restrict__ out) {
    if (threadIdx.x == 0) out[N_LEAVES] = 0.0f;
}

// One wave handles 4 consecutive nodes; block (4 waves) handles 16 nodes.
// Grid = 2048 blocks -> 32768 node slots (guard the last one).
__global__ __launch_bounds__(256) void delta_total_kernel(
        const float* __restrict__ deltas,
        const float* __restrict__ heights,
        float* __restrict__ out) {
    const int lane = threadIdx.x & 63;
    const int wave = threadIdx.x >> 6;                 // 0..3
    const int nodeBase = blockIdx.x * 16 + wave * 4;

    float partial = 0.0f;
    for (int k = 0; k < 4; ++k) {
        const int node = nodeBase + k;                 // wave-uniform
        if (node >= N_NODES) break;
        const float4* row = (const float4*)(deltas + (size_t)node * DIM);
        float4 a = row[lane];        // comps [4*lane, 4*lane+4)        — coalesced 1 KiB
        float4 b = row[lane + 64];   // comps [256+4*lane, 256+4*lane+4) — coalesced 1 KiB
        float s = a.x*a.x + a.y*a.y + a.z*a.z + a.w*a.w
                + b.x*b.x + b.y*b.y + b.z*b.z + b.w*b.w;
        // wave64 butterfly reduce
        for (int off = 32; off; off >>= 1) s += __shfl_xor(s, off, 64);
        if (lane == 0) {
            if (node == 0) {
                partial += s;
            } else {
                float br = heights[node] - heights[(node - 1) >> 1];
                br = fmaxf(br, MIN_DIST);
                partial += s / br;
            }
        }
    }

    __shared__ float lds[4];
    if (lane == 0) lds[wave] = partial;
    __syncthreads();
    if (threadIdx.x == 0) {
        float s = lds[0] + lds[1] + lds[2] + lds[3];
        atomicAdd(out + N_LEAVES, s);   // 2048 atomics total — negligible contention
    }
}

// One wave per leaf. Lane holds 8 components (two float4 slices of the 512-dim row).
// Ancestor chain is wave-uniform -> scalar address arithmetic, coalesced float4 loads.
__global__ __launch_bounds__(256) void leaf_dot_kernel(
        const float* __restrict__ x,
        const float* __restrict__ deltas,
        float* __restrict__ out) {
    const int lane = threadIdx.x & 63;
    const int wave = threadIdx.x >> 6;                 // 0..3
    const int leaf = blockIdx.x * 4 + wave;            // grid exact: 4096*4 = 16384

    float4 w0 = make_float4(0.f, 0.f, 0.f, 0.f);
    float4 w1 = make_float4(0.f, 0.f, 0.f, 0.f);

    int node = N_LEAVES - 1 + leaf;                    // leaf's heap index
    #pragma unroll
    for (int l = 0; l < 15; ++l) {                     // 15 levels incl. root
        const float4* row = (const float4*)(deltas + (size_t)node * DIM);
        float4 a = row[lane];
        float4 b = row[lane + 64];
        w0.x += a.x; w0.y += a.y; w0.z += a.z; w0.w += a.w;
        w1.x += b.x; w1.y += b.y; w1.z += b.z; w1.w += b.w;
        node = (node - 1) >> 1;
    }

    const float4* xr = (const float4*)(x + (size_t)leaf * DIM);
    float4 xa = xr[lane];
    float4 xb = xr[lane + 64];
    float dot = xa.x*w0.x + xa.y*w0.y + xa.z*w0.z + xa.w*w0.w
              + xb.x*w1.x + xb.y*w1.y + xb.z*w1.z + xb.w*w1.w;

    for (int off = 32; off; off >>= 1) dot += __shfl_xor(dot, off, 64);
    if (lane == 0) out[leaf] = dot;
}

extern "C" void kernel_launch(void* const* d_in, const int* in_sizes, int n_in,
                              void* d_out, int out_size, void* d_ws, size_t ws_size,
                              hipStream_t stream) {
    const float* x       = (const float*)d_in[0];
    const float* deltas  = (const float*)d_in[1];
    const float* heights = (const float*)d_in[2];
    float* out = (float*)d_out;

    zero_scalar_kernel<<<1, 64, 0, stream>>>(out);
    // delta_total first: streams all 64 MiB of deltas once -> warms L3 for leaf_dot.
    delta_total_kernel<<<2048, 256, 0, stream>>>(deltas, heights, out);
    leaf_dot_kernel<<<4096, 256, 0, stream>>>(x, deltas, out);
}

// Round 2
// 125.587 us; speedup vs baseline: 1.2733x; 1.2733x over previous
//
#include <hip/hip_runtime.h>

// TreeModel fused kernel.
// Tree: complete binary heap, 15 levels (0..14), nodes 0..32766, leaves = nodes 16383..32766.
// out[0..16383] = dot(x[leaf], sum of deltas rows on root->leaf path)
// out[16384]    = sq[0] + sum_{n>=1} sq[n] / max(heights[n]-heights[parent(n)], 1e-7)

constexpr int   N_LEAVES = 16384;
constexpr int   N_NODES  = 2 * N_LEAVES - 1;   // 32767
constexpr int   DIM      = 512;
constexpr float MIN_DIST = 1e-7f;
constexpr int   N_UPPER  = 2047;               // nodes at levels 0..10

__device__ __forceinline__ float4 f4add(float4 a, float4 b) {
    return make_float4(a.x + b.x, a.y + b.y, a.z + b.z, a.w + b.w);
}
__device__ __forceinline__ float f4dot(float4 a, float4 b) {
    return a.x * b.x + a.y * b.y + a.z * b.z + a.w * b.w;
}
__device__ __forceinline__ float f4sq(float4 a) { return f4dot(a, a); }

__global__ void zero_scalar_kernel(float* __restrict__ out) {
    if (threadIdx.x == 0) out[N_LEAVES] = 0.0f;
}

// Block = 256 threads (4 waves) = 16 consecutive leaves (4 per wave). Grid = 1024.
__global__ __launch_bounds__(256) void fused_kernel(
        const float* __restrict__ x,
        const float* __restrict__ deltas,
        const float* __restrict__ heights,
        float* __restrict__ out) {
    __shared__ __align__(16) float wtop[DIM];   // shared ancestor sum, levels 0..10
    __shared__ float sqred[4];

    const int tid  = threadIdx.x;
    const int lane = tid & 63;
    const int wave = tid >> 6;
    const int b    = blockIdx.x;                // leaves 16b .. 16b+15

    float sq_acc = 0.0f;  // per-lane partial of delta_total (already scaled by 1/branch)

    // ---- Stage 0: upper nodes (levels 0..10) sq contribution.
    // Block b owns nodes 2b (wave 0) and 2b+1 (wave 1); covers 0..2046 exactly once.
    if (wave < 2) {
        const int n = 2 * b + wave;
        if (n < N_UPPER) {
            const float4* row = (const float4*)(deltas + (size_t)n * DIM);
            float4 a = row[lane];
            float4 c = row[lane + 64];
            float scale = 1.0f;                  // node 0: raw sq, no branch division
            if (n > 0) {
                float br = heights[n] - heights[(n - 1) >> 1];
                scale = 1.0f / fmaxf(br, MIN_DIST);
            }
            sq_acc += (f4sq(a) + f4sq(c)) * scale;
        }
    }

    // ---- Stage 1: shared ancestor sum (levels 0..10) into LDS.
    // Thread t accumulates elements [2t, 2t+1] over the 11 shared rows (all loads independent).
    {
        float2 acc = make_float2(0.0f, 0.0f);
        #pragma unroll
        for (int l = 0; l <= 10; ++l) {
            const int node = ((1 << l) - 1) + (b >> (10 - l));   // level-l ancestor of leaf group
            const float2* row = (const float2*)(deltas + (size_t)node * DIM);
            float2 v = row[tid];
            acc.x += v.x; acc.y += v.y;
        }
        wtop[2 * tid]     = acc.x;
        wtop[2 * tid + 1] = acc.y;
    }
    __syncthreads();

    // Lane's 8-element slice of the shared top sum.
    const float4 t0 = ((const float4*)wtop)[lane];
    const float4 t1 = ((const float4*)wtop)[lane + 64];

    // ---- Stage 2: per-leaf work. Wave handles 4 leaves; 10 independent float4 loads each.
    #pragma unroll
    for (int k = 0; k < 4; ++k) {
        const int leaf = b * 16 + wave * 4 + k;
        const int n14 = (N_LEAVES - 1) + leaf;
        const int n13 = (n14 - 1) >> 1;
        const int n12 = (n13 - 1) >> 1;
        const int n11 = (n12 - 1) >> 1;

        const float4* r14 = (const float4*)(deltas + (size_t)n14 * DIM);
        const float4* r13 = (const float4*)(deltas + (size_t)n13 * DIM);
        const float4* r12 = (const float4*)(deltas + (size_t)n12 * DIM);
        const float4* r11 = (const float4*)(deltas + (size_t)n11 * DIM);
        const float4* xr  = (const float4*)(x      + (size_t)leaf * DIM);

        float4 a14 = r14[lane], c14 = r14[lane + 64];
        float4 a13 = r13[lane], c13 = r13[lane + 64];
        float4 a12 = r12[lane], c12 = r12[lane + 64];
        float4 a11 = r11[lane], c11 = r11[lane + 64];
        float4 xa  = xr[lane],  xc  = xr[lane + 64];

        float4 w0 = f4add(f4add(t0, a14), f4add(a13, f4add(a12, a11)));
        float4 w1 = f4add(f4add(t1, c14), f4add(c13, f4add(c12, c11)));

        float dot = f4dot(xa, w0) + f4dot(xc, w1);
        #pragma unroll
        for (int off = 32; off; off >>= 1) dot += __shfl_xor(dot, off, 64);
        if (lane == 0) out[leaf] = dot;

        // sq ownership (globally consistent, wave-uniform conditions):
        // level 14 always; 13 iff leaf&1==0; 12 iff leaf&3==0; 11 iff leaf&7==0.
        {
            float br = heights[n14] - heights[n13];
            sq_acc += (f4sq(a14) + f4sq(c14)) / fmaxf(br, MIN_DIST);
        }
        if ((leaf & 1) == 0) {
            float br = heights[n13] - heights[n12];
            sq_acc += (f4sq(a13) + f4sq(c13)) / fmaxf(br, MIN_DIST);
        }
        if ((leaf & 3) == 0) {
            float br = heights[n12] - heights[n11];
            sq_acc += (f4sq(a12) + f4sq(c12)) / fmaxf(br, MIN_DIST);
        }
        if ((leaf & 7) == 0) {
            const int n10 = (n11 - 1) >> 1;
            float br = heights[n11] - heights[n10];
            sq_acc += (f4sq(a11) + f4sq(c11)) / fmaxf(br, MIN_DIST);
        }
    }

    // ---- Final: block-reduce sq_acc, one atomic per block (1024 total).
    #pragma unroll
    for (int off = 32; off; off >>= 1) sq_acc += __shfl_xor(sq_acc, off, 64);
    if (lane == 0) sqred[wave] = sq_acc;
    __syncthreads();
    if (tid == 0)
        atomicAdd(out + N_LEAVES, sqred[0] + sqred[1] + sqred[2] + sqred[3]);
}

extern "C" void kernel_launch(void* const* d_in, const int* in_sizes, int n_in,
                              void* d_out, int out_size, void* d_ws, size_t ws_size,
                              hipStream_t stream) {
    const float* x       = (const float*)d_in[0];
    const float* deltas  = (const float*)d_in[1];
    const float* heights = (const float*)d_in[2];
    float* out = (float*)d_out;

    zero_scalar_kernel<<<1, 64, 0, stream>>>(out);
    fused_kernel<<<N_LEAVES / 16, 256, 0, stream>>>(x, deltas, heights, out);
}